// Round 5
// baseline (66.675 us; speedup 1.0000x reference)
//
#include <hip/hip_runtime.h>

#define NV 5000
#define NF 1000
#define HH 256
#define NPIX (HH*HH)
#define NTILE 256          // 16x16 tiles of 16x16 pixels
#define NGROUP 8
#define FPG (NF/NGROUP)    // 125 faces per group
#define TCUT 25.0f         // exp2 cutoff: prob < 2^-25 -> negligible

// ---------------- kernel 1: vertex transform + projection (VERBATIM r1) ----
__global__ void k_prep_vertex(const float* __restrict__ vtx,
                              const float* __restrict__ cam,
                              float* __restrict__ out,
                              unsigned* __restrict__ counter,
                              float2* __restrict__ xy) {
    int i = blockIdx.x * blockDim.x + threadIdx.x;
    if (i == 0) { out[0] = 0.0f; counter[0] = 0u; }
    if (i >= NV) return;
    float ex = cam[0], ey = cam[1], ez = cam[2];
    // z_ax = normalize(-eye)
    float zn = sqrtf(ex*ex + ey*ey + ez*ez) + 1e-8f;
    float zx = -ex/zn, zy = -ey/zn, zz = -ez/zn;
    // x_ax = normalize(cross((0,1,0), z)) = normalize((zz, 0, -zx))
    float xn = sqrtf(zz*zz + zx*zx) + 1e-8f;
    float xx = zz/xn, xy_ = 0.0f, xz = -zx/xn;
    // y_ax = cross(z, x)
    float yx = zy*xz - zz*xy_;
    float yy = zz*xx - zx*xz;
    float yz = zx*xy_ - zy*xx;
    float vx = vtx[i*3+0]-ex, vy = vtx[i*3+1]-ey, vz = vtx[i*3+2]-ez;
    float cxx = vx*xx + vy*xy_ + vz*xz;
    float cyy = vx*yx + vy*yy  + vz*yz;
    float czz = vx*zx + vy*zy  + vz*zz;
    const float w = 0.5773502691896258f;   // tan(30 deg)
    float den = czz*w + 1e-8f;
    xy[i] = make_float2(cxx/den, cyy/den);
}

// ---------------- kernel 2: per-face edge coefficients (VERBATIM r1) -------
__global__ void k_face(const int* __restrict__ faces,
                       const float2* __restrict__ xy,
                       float4* __restrict__ a4,
                       float4* __restrict__ b4,
                       float* __restrict__ c1) {
    int f = blockIdx.x * blockDim.x + threadIdx.x;
    if (f >= NF) return;
    int i0 = faces[f*3+0], i1 = faces[f*3+1], i2 = faces[f*3+2];
    float2 p0 = xy[i0], p1 = xy[i1], p2 = xy[i2];
    float eax = p1.x-p0.x, eay = p1.y-p0.y;
    float ebx = p2.x-p0.x, eby = p2.y-p0.y;
    float cr = eax*eby - eay*ebx;
    float s = (cr > 0.0f) ? 1.0f : ((cr < 0.0f) ? -1.0f : 0.0f);
    const float m = -144.26950408889634f * s;   // -log2(e)/SHARP * orient

    float A0,B0,C0,A1,B1,C1,A2,B2,C2;
    {   // edge 0: p0 -> p1
        float ex_ = p1.x-p0.x, ey_ = p1.y-p0.y;
        float el = sqrtf(ex_*ex_+ey_*ey_) + 1e-8f;
        A0 = (ex_/el)*m; B0 = (-ey_/el)*m; C0 = ((ey_*p0.x - ex_*p0.y)/el)*m;
    }
    {   // edge 1: p1 -> p2
        float ex_ = p2.x-p1.x, ey_ = p2.y-p1.y;
        float el = sqrtf(ex_*ex_+ey_*ey_) + 1e-8f;
        A1 = (ex_/el)*m; B1 = (-ey_/el)*m; C1 = ((ey_*p1.x - ex_*p1.y)/el)*m;
    }
    {   // edge 2: p2 -> p0
        float ex_ = p0.x-p2.x, ey_ = p0.y-p2.y;
        float el = sqrtf(ex_*ex_+ey_*ey_) + 1e-8f;
        A2 = (ex_/el)*m; B2 = (-ey_/el)*m; C2 = ((ey_*p2.x - ex_*p2.y)/el)*m;
    }
    a4[f] = make_float4(A0, B0, C0, A1);
    b4[f] = make_float4(B1, C1, A2, B2);
    c1[f] = C2;
}

// -------- kernel 3: render, 16x16 tile per block + in-block face culling ----
__global__ __launch_bounds__(256) void k_render(
        const float4* __restrict__ a4,
        const float4* __restrict__ b4,
        const float*  __restrict__ c1,
        float* __restrict__ partials) {
    __shared__ float4 sa[FPG];
    __shared__ float4 sb[FPG];
    __shared__ float  sc[FPG];
    __shared__ int    flags[FPG];
    __shared__ int    list[FPG];
    __shared__ int    cnt;

    const int g    = blockIdx.y;
    const int tile = blockIdx.x;
    const int fbeg = g * FPG;
    const int t    = threadIdx.x;

    // stage this group's coefficients (proven in round 4)
    if (t < FPG) {
        sa[t] = a4[fbeg + t];
        sb[t] = b4[fbeg + t];
        sc[t] = c1[fbeg + t];
    }
    __syncthreads();

    const int tx = tile & 15, ty = tile >> 4;
    const float s  = 2.0f / HH;
    const float cx = (tx*16 + 8) * s - 1.0f;   // center of the tile's pixel-center box
    const float cy = (ty*16 + 8) * s - 1.0f;
    const float h  = 7.5f * s;                 // half-extent of pixel centers

    // conservative per-tile test: bound <= min over tile pixels of max-edge t
    if (t < FPG) {
        float4 qa = sa[t]; float4 qb = sb[t]; float qc = sc[t];
        float b0 = fmaf(qa.x, cy, fmaf(qa.y, cx, qa.z)) - (fabsf(qa.x)+fabsf(qa.y))*h;
        float b1 = fmaf(qa.w, cy, fmaf(qb.x, cx, qb.y)) - (fabsf(qa.w)+fabsf(qb.x))*h;
        float b2 = fmaf(qb.z, cy, fmaf(qb.w, cx, qc))   - (fabsf(qb.z)+fabsf(qb.w))*h;
        flags[t] = (fmaxf(fmaxf(b0, b1), b2) <= TCUT) ? 1 : 0;
    }
    __syncthreads();

    // wave 0: order-preserving ballot compaction of 125 flags
    if (t < 64) {
        int l = t;
        bool k0 = (flags[l] != 0);
        bool k1 = (64 + l < FPG) ? (flags[64 + l] != 0) : false;
        unsigned long long m0 = __ballot(k0);
        unsigned long long m1 = __ballot(k1);
        unsigned long long below = (1ull << l) - 1ull;
        if (k0) list[__popcll(m0 & below)] = l;
        if (k1) list[__popcll(m0) + __popcll(m1 & below)] = 64 + l;
        if (l == 0) cnt = __popcll(m0) + __popcll(m1);
    }
    __syncthreads();

    const int col = tx*16 + (t & 15);
    const int row = ty*16 + (t >> 4);
    const float px = (col + 0.5f) * s - 1.0f;
    const float py = (row + 0.5f) * s - 1.0f;

    float acc = 0.0f;
    const int n = cnt;
    for (int k = 0; k < n; ++k) {
        int j = list[k];
        float4 qa = sa[j];
        float4 qb = sb[j];
        float  qc = sc[j];
        float t0 = fmaf(qa.x, py, fmaf(qa.y, px, qa.z));
        float t1 = fmaf(qa.w, py, fmaf(qb.x, px, qb.y));
        float t2 = fmaf(qb.z, py, fmaf(qb.w, px, qc));
        float tmax = fmaxf(fmaxf(t0, t1), t2);
        if (__any(tmax <= TCUT)) {
            float e0 = __builtin_amdgcn_exp2f(t0);
            float e1 = __builtin_amdgcn_exp2f(t1);
            float e2 = __builtin_amdgcn_exp2f(t2);
            float Pm = (1.0f+e0) * (1.0f+e1) * (1.0f+e2);
            float prob = __builtin_amdgcn_rcpf(Pm);
            float q = fmaxf(1.0f - prob, 1e-6f);
            acc += __builtin_amdgcn_logf(q);      // log2(1-prob)
        }
    }
    partials[g * NPIX + row * HH + col] = acc;    // unconditional store
}

// ---------------- kernel 4: combine + loss reduction (VERBATIM r1) ----------
__global__ __launch_bounds__(256) void k_combine(
        const float* __restrict__ partials,
        const float* __restrict__ ref,
        float* __restrict__ out) {
    int pix = blockIdx.x * 256 + threadIdx.x;
    float tot = 0.0f;
    #pragma unroll
    for (int g = 0; g < NGROUP; ++g) tot += partials[g * NPIX + pix];
    float sil = 1.0f - __builtin_amdgcn_exp2f(tot);   // 1 - exp(log_bg)
    float d = sil - ref[pix];
    float sq = d * d;
    #pragma unroll
    for (int off = 32; off > 0; off >>= 1)
        sq += __shfl_down(sq, off, 64);
    __shared__ float wsum[4];
    int wid = threadIdx.x >> 6;
    if ((threadIdx.x & 63) == 0) wsum[wid] = sq;
    __syncthreads();
    if (threadIdx.x == 0)
        atomicAdd(out, wsum[0] + wsum[1] + wsum[2] + wsum[3]);
}

extern "C" void kernel_launch(void* const* d_in, const int* in_sizes, int n_in,
                              void* d_out, int out_size, void* d_ws, size_t ws_size,
                              hipStream_t stream) {
    const float* vtx   = (const float*)d_in[0];   // (1,5000,3) f32
    const int*   faces = (const int*)  d_in[1];   // (1,1000,3) i32
    const float* cam   = (const float*)d_in[2];   // (3,) f32
    const float* ref   = (const float*)d_in[3];   // (256,256) f32
    float* out = (float*)d_out;

    char* ws = (char*)d_ws;
    unsigned* counter = (unsigned*)(ws + 0);
    float2*   xy      = (float2*)  (ws + 256);     // 40000 B
    float4*   a4      = (float4*)  (ws + 40448);   // 16000 B
    float4*   b4      = (float4*)  (ws + 56448);   // 16000 B
    float*    c1      = (float*)   (ws + 72448);   // 4000 B
    float*    part    = (float*)   (ws + 76800);   // 8*65536*4 = 2 MiB

    k_prep_vertex<<<dim3((NV+255)/256),     dim3(256), 0, stream>>>(vtx, cam, out, counter, xy);
    k_face       <<<dim3((NF+255)/256),     dim3(256), 0, stream>>>(faces, xy, a4, b4, c1);
    k_render     <<<dim3(NTILE, NGROUP),    dim3(256), 0, stream>>>(a4, b4, c1, part);
    k_combine    <<<dim3(NPIX/256),         dim3(256), 0, stream>>>(part, ref, out);
}

// Round 6
// 38.743 us; speedup vs baseline: 1.7210x; 1.7210x over previous
//
#include <hip/hip_runtime.h>

#define NV 5000
#define NF 1000
#define HH 256
#define NPIX (HH*HH)
#define NTILE 256          // 16x16 tiles of 16x16 pixels
#define CS 32              // faces per render chunk
#define NCHK 32            // CS*NCHK = 1024 >= NF slots per tile
#define TCUT 25.0f         // exp2 cutoff: prob < 2^-25 -> negligible

// ---------------- kernel 1: vertex transform + projection (VERBATIM r1) ----
__global__ void k_prep_vertex(const float* __restrict__ vtx,
                              const float* __restrict__ cam,
                              float* __restrict__ out,
                              unsigned* __restrict__ counter,
                              float2* __restrict__ xy) {
    int i = blockIdx.x * blockDim.x + threadIdx.x;
    if (i == 0) { out[0] = 0.0f; counter[0] = 0u; }
    if (i >= NV) return;
    float ex = cam[0], ey = cam[1], ez = cam[2];
    // z_ax = normalize(-eye)
    float zn = sqrtf(ex*ex + ey*ey + ez*ez) + 1e-8f;
    float zx = -ex/zn, zy = -ey/zn, zz = -ez/zn;
    // x_ax = normalize(cross((0,1,0), z)) = normalize((zz, 0, -zx))
    float xn = sqrtf(zz*zz + zx*zx) + 1e-8f;
    float xx = zz/xn, xy_ = 0.0f, xz = -zx/xn;
    // y_ax = cross(z, x)
    float yx = zy*xz - zz*xy_;
    float yy = zz*xx - zx*xz;
    float yz = zx*xy_ - zy*xx;
    float vx = vtx[i*3+0]-ex, vy = vtx[i*3+1]-ey, vz = vtx[i*3+2]-ez;
    float cxx = vx*xx + vy*xy_ + vz*xz;
    float cyy = vx*yx + vy*yy  + vz*yz;
    float czz = vx*zx + vy*zy  + vz*zz;
    const float w = 0.5773502691896258f;   // tan(30 deg)
    float den = czz*w + 1e-8f;
    xy[i] = make_float2(cxx/den, cyy/den);
}

// ---------------- kernel 2: per-face edge coefficients (VERBATIM r1) -------
__global__ void k_face(const int* __restrict__ faces,
                       const float2* __restrict__ xy,
                       float4* __restrict__ a4,
                       float4* __restrict__ b4,
                       float* __restrict__ c1) {
    int f = blockIdx.x * blockDim.x + threadIdx.x;
    if (f >= NF) return;
    int i0 = faces[f*3+0], i1 = faces[f*3+1], i2 = faces[f*3+2];
    float2 p0 = xy[i0], p1 = xy[i1], p2 = xy[i2];
    float eax = p1.x-p0.x, eay = p1.y-p0.y;
    float ebx = p2.x-p0.x, eby = p2.y-p0.y;
    float cr = eax*eby - eay*ebx;
    float s = (cr > 0.0f) ? 1.0f : ((cr < 0.0f) ? -1.0f : 0.0f);
    const float m = -144.26950408889634f * s;   // -log2(e)/SHARP * orient

    float A0,B0,C0,A1,B1,C1,A2,B2,C2;
    {   // edge 0: p0 -> p1
        float ex_ = p1.x-p0.x, ey_ = p1.y-p0.y;
        float el = sqrtf(ex_*ex_+ey_*ey_) + 1e-8f;
        A0 = (ex_/el)*m; B0 = (-ey_/el)*m; C0 = ((ey_*p0.x - ex_*p0.y)/el)*m;
    }
    {   // edge 1: p1 -> p2
        float ex_ = p2.x-p1.x, ey_ = p2.y-p1.y;
        float el = sqrtf(ex_*ex_+ey_*ey_) + 1e-8f;
        A1 = (ex_/el)*m; B1 = (-ey_/el)*m; C1 = ((ey_*p1.x - ex_*p1.y)/el)*m;
    }
    {   // edge 2: p2 -> p0
        float ex_ = p0.x-p2.x, ey_ = p0.y-p2.y;
        float el = sqrtf(ex_*ex_+ey_*ey_) + 1e-8f;
        A2 = (ex_/el)*m; B2 = (-ey_/el)*m; C2 = ((ey_*p2.x - ex_*p2.y)/el)*m;
    }
    a4[f] = make_float4(A0, B0, C0, A1);
    b4[f] = make_float4(B1, C1, A2, B2);
    c1[f] = C2;
}

// -------- kernel 3: per-tile face binning (order-preserving) + zero part ----
__global__ __launch_bounds__(256) void k_bin(
        const float4* __restrict__ a4,
        const float4* __restrict__ b4,
        const float*  __restrict__ c1,
        int* __restrict__ list,
        int* __restrict__ count,
        float* __restrict__ part) {
    const int tile = blockIdx.x;
    const int t    = threadIdx.x;
    part[tile*256 + t] = 0.0f;              // 256 blocks x 256 thr == NPIX

    const int lane = t & 63, wid = t >> 6;
    const int tx = tile & 15, ty = tile >> 4;
    const float s  = 2.0f / HH;
    const float cx = (tx*16 + 8) * s - 1.0f;
    const float cy = (ty*16 + 8) * s - 1.0f;
    const float h  = 7.5f * s;

    __shared__ int wc[4];
    int cnt = 0;
    for (int base = 0; base < NCHK*CS; base += 256) {
        int f = base + t;
        bool keep = false;
        if (f < NF) {
            float4 qa = a4[f]; float4 qb = b4[f]; float qc = c1[f];
            float b0 = fmaf(qa.x, cy, fmaf(qa.y, cx, qa.z)) - (fabsf(qa.x)+fabsf(qa.y))*h;
            float b1 = fmaf(qa.w, cy, fmaf(qb.x, cx, qb.y)) - (fabsf(qa.w)+fabsf(qb.x))*h;
            float b2 = fmaf(qb.z, cy, fmaf(qb.w, cx, qc))   - (fabsf(qb.z)+fabsf(qb.w))*h;
            keep = (fmaxf(fmaxf(b0, b1), b2) <= TCUT);
        }
        unsigned long long m = __ballot(keep);
        if (lane == 0) wc[wid] = __popcll(m);
        __syncthreads();
        int wbase = cnt;
        for (int wq = 0; wq < wid; ++wq) wbase += wc[wq];
        if (keep) {
            int pos = wbase + __popcll(m & ((1ull << lane) - 1ull));
            list[tile*(NCHK*CS) + pos] = f;
        }
        cnt += wc[0] + wc[1] + wc[2] + wc[3];
        __syncthreads();
    }
    if (t == 0) count[tile] = cnt;
}

// -------- kernel 4: render, one (tile, 32-face chunk) per block -------------
__global__ __launch_bounds__(256) void k_render(
        const float4* __restrict__ a4,
        const float4* __restrict__ b4,
        const float*  __restrict__ c1,
        const int* __restrict__ list,
        const int* __restrict__ count,
        float* __restrict__ part) {
    const int tile = blockIdx.x;
    const int n    = count[tile];
    const int beg  = blockIdx.y * CS;
    if (beg >= n) return;
    const int nf = min(n - beg, CS);

    __shared__ float4 sa[CS];
    __shared__ float4 sb[CS];
    __shared__ float  sc[CS];
    const int t = threadIdx.x;
    if (t < nf) {
        int f = list[tile*(NCHK*CS) + beg + t];
        sa[t] = a4[f];
        sb[t] = b4[f];
        sc[t] = c1[f];
    }
    __syncthreads();

    const int tx = tile & 15, ty = tile >> 4;
    const int col = tx*16 + (t & 15);
    const int row = ty*16 + (t >> 4);
    const float s  = 2.0f / HH;
    const float px = (col + 0.5f) * s - 1.0f;
    const float py = (row + 0.5f) * s - 1.0f;

    float acc = 0.0f;
    for (int k = 0; k < nf; ++k) {
        float4 qa = sa[k];
        float4 qb = sb[k];
        float  qc = sc[k];
        float t0 = fmaf(qa.x, py, fmaf(qa.y, px, qa.z));
        float t1 = fmaf(qa.w, py, fmaf(qb.x, px, qb.y));
        float t2 = fmaf(qb.z, py, fmaf(qb.w, px, qc));
        float tmax = fmaxf(fmaxf(t0, t1), t2);
        if (__any(tmax <= TCUT)) {
            float e0 = __builtin_amdgcn_exp2f(t0);
            float e1 = __builtin_amdgcn_exp2f(t1);
            float e2 = __builtin_amdgcn_exp2f(t2);
            float Pm = (1.0f+e0) * (1.0f+e1) * (1.0f+e2);
            float prob = __builtin_amdgcn_rcpf(Pm);
            float q = fmaxf(1.0f - prob, 1e-6f);
            acc += __builtin_amdgcn_logf(q);      // log2(1-prob)
        }
    }
    atomicAdd(&part[row*HH + col], acc);          // device-scope float add
}

// ---------------- kernel 5: combine + loss reduction ------------------------
__global__ __launch_bounds__(256) void k_combine(
        const float* __restrict__ part,
        const float* __restrict__ ref,
        float* __restrict__ out) {
    int pix = blockIdx.x * 256 + threadIdx.x;
    float sil = 1.0f - __builtin_amdgcn_exp2f(part[pix]);   // 1 - exp(log_bg)
    float d = sil - ref[pix];
    float sq = d * d;
    #pragma unroll
    for (int off = 32; off > 0; off >>= 1)
        sq += __shfl_down(sq, off, 64);
    __shared__ float wsum[4];
    int wid = threadIdx.x >> 6;
    if ((threadIdx.x & 63) == 0) wsum[wid] = sq;
    __syncthreads();
    if (threadIdx.x == 0)
        atomicAdd(out, wsum[0] + wsum[1] + wsum[2] + wsum[3]);
}

extern "C" void kernel_launch(void* const* d_in, const int* in_sizes, int n_in,
                              void* d_out, int out_size, void* d_ws, size_t ws_size,
                              hipStream_t stream) {
    const float* vtx   = (const float*)d_in[0];   // (1,5000,3) f32
    const int*   faces = (const int*)  d_in[1];   // (1,1000,3) i32
    const float* cam   = (const float*)d_in[2];   // (3,) f32
    const float* ref   = (const float*)d_in[3];   // (256,256) f32
    float* out = (float*)d_out;

    char* ws = (char*)d_ws;
    unsigned* counter = (unsigned*)(ws + 0);
    float2*   xy      = (float2*)  (ws + 256);      // 40000 B
    float4*   a4      = (float4*)  (ws + 40448);    // 16000 B
    float4*   b4      = (float4*)  (ws + 56448);    // 16000 B
    float*    c1      = (float*)   (ws + 72448);    //  4000 B
    int*      count   = (int*)     (ws + 76800);    //  1024 B
    int*      list    = (int*)     (ws + 77824);    // 256*1024*4 = 1 MiB
    float*    part    = (float*)   (ws + 1126400);  // 256 KiB (end ~1.39 MB)

    k_prep_vertex<<<dim3((NV+255)/256),  dim3(256), 0, stream>>>(vtx, cam, out, counter, xy);
    k_face       <<<dim3((NF+255)/256),  dim3(256), 0, stream>>>(faces, xy, a4, b4, c1);
    k_bin        <<<dim3(NTILE),         dim3(256), 0, stream>>>(a4, b4, c1, list, count, part);
    k_render     <<<dim3(NTILE, NCHK),   dim3(256), 0, stream>>>(a4, b4, c1, list, count, part);
    k_combine    <<<dim3(NPIX/256),      dim3(256), 0, stream>>>(part, ref, out);
}